// Round 4
// baseline (295.547 us; speedup 1.0000x reference)
//
#include <hip/hip_runtime.h>
#include <hip/hip_bf16.h>

// Problem dims
#define B_  2
#define C_  256
#define N_  4096
#define R_  8
#define G_  4
#define CG_ 64

typedef __attribute__((ext_vector_type(8))) short short8;
typedef __attribute__((ext_vector_type(4))) float f32x4;

#define MFMA16(a, b, c) __builtin_amdgcn_mfma_f32_16x16x32_bf16((a), (b), (c), 0, 0, 0)
#define EXP2F(x) __builtin_amdgcn_exp2f(x)
#define LOG2E 1.44269504088896f

__device__ inline unsigned int pk2(float a, float b) {
    union { __hip_bfloat162 h; unsigned int u; } cv;
    cv.h = __float22bfloat162_rn(float2{a, b});
    return cv.u;
}
__device__ inline unsigned short f2bf(float f) {
    union { __hip_bfloat16 h; unsigned short u; } cv;
    cv.h = __float2bfloat16(f);
    return cv.u;
}

// Workspace layout (ushort units unless noted):
//  qT  bf16 [d][b][n][8] (log2e folded)   : 0        (131072)
//  kT  bf16 [d][b][m][8]                  : 131072   (131072)
//  v   bf16 [d][b][c][n]                  : 262144   (4194304)
//  wqk bf16 [s][16][256] (rows0-7 q*log2e): 4456448  (8192)
//  wv  bf16 [s][4][64][64]                : 4464640  (32768)
//  l2z f32  [d][b][n] = -log2(Z)          : float idx 2248704 (16384)
#define QT_OFF   0
#define KT_OFF   131072
#define V_OFF    262144
#define WQK_OFF  4456448
#define WV_OFF   4464640
#define L2Z_OFFF 2248704
// total ~9.1 MB

// ---------------------------------------------------------------------------
// Kernel 0: pack weights to bf16 once. grid(2) -> block s.
// ---------------------------------------------------------------------------
__global__ __launch_bounds__(256) void wpack(
    const float* __restrict__ qLw, const float* __restrict__ kLw,
    const float* __restrict__ vLw,
    const float* __restrict__ qUw, const float* __restrict__ kUw,
    const float* __restrict__ vUw,
    unsigned short* __restrict__ wsu)
{
    const int s = blockIdx.x;
    const float* wq = s ? qUw : qLw;
    const float* wk = s ? kUw : kLw;
    const float* wv = s ? vUw : vLw;

    for (int i = threadIdx.x; i < 16 * C_; i += 256) {
        const int o = i >> 8, c = i & 255;
        const float v = (o < 8) ? wq[o * C_ + c] * LOG2E : wk[(o - 8) * C_ + c];
        wsu[WQK_OFF + s * (16 * C_) + i] = f2bf(v);
    }
    for (int i = threadIdx.x; i < G_ * CG_ * CG_; i += 256)
        wsu[WV_OFF + s * (G_ * CG_ * CG_) + i] = f2bf(wv[i]);
}

// ---------------------------------------------------------------------------
// Kernel 1: fused proj + grouped conv, MFMA, transposed-LDS staging.
// grid(128 n-tiles of 32, 1, 4: z = s*2+b), block 256 (4 waves).
// wave (nc = w&1 -> n-chunk 16, gh = w>>1). gh0: proj + groups 0,1; gh1: g2,3.
// ---------------------------------------------------------------------------
#define XS2 264   // xs row stride in shorts (c-dim 256 + pad 8)

__global__ __launch_bounds__(256) void fused_pre(
    const float* __restrict__ fL, const float* __restrict__ fU,
    const float* __restrict__ qLb, const float* __restrict__ kLb,
    const float* __restrict__ vLb,
    const float* __restrict__ qUb, const float* __restrict__ kUb,
    const float* __restrict__ vUb,
    unsigned short* __restrict__ wsu)
{
    const int s  = blockIdx.z >> 1;
    const int b  = blockIdx.z & 1;
    const int n0 = blockIdx.x * 32;
    const int t  = threadIdx.x;

    const float* x  = (s ? fU : fL) + (size_t)b * C_ * N_;
    const float* bq = s ? qUb : qLb;
    const float* bk = s ? kUb : kLb;
    const float* bv = s ? vUb : vLb;
    const int dq = s, dk = 1 - s, dv = 1 - s;

    const unsigned short* wqk = wsu + WQK_OFF + s * (16 * C_);
    const unsigned short* wv  = wsu + WV_OFF + s * (G_ * CG_ * CG_);

    __shared__ unsigned short xs[32 * XS2];   // [n][c] bf16, transposed

    // ---- stage x (fp32 [c][n]) -> xs (bf16 [n][c]), pairwise dword writes ----
    {
        const int cp = t >> 1;           // c-pair 0..127
        const int nh = (t & 1) * 16;     // n-half
        const float* r0 = x + (size_t)(2 * cp) * N_ + n0 + nh;
        const float* r1 = r0 + N_;
        float4 a[4], bb[4];
#pragma unroll
        for (int j = 0; j < 4; j++) {
            a[j]  = *reinterpret_cast<const float4*>(r0 + j * 4);
            bb[j] = *reinterpret_cast<const float4*>(r1 + j * 4);
        }
        unsigned int* xd = reinterpret_cast<unsigned int*>(xs);
#pragma unroll
        for (int j = 0; j < 4; j++) {
            xd[(nh + j * 4 + 0) * (XS2 / 2) + cp] = pk2(a[j].x, bb[j].x);
            xd[(nh + j * 4 + 1) * (XS2 / 2) + cp] = pk2(a[j].y, bb[j].y);
            xd[(nh + j * 4 + 2) * (XS2 / 2) + cp] = pk2(a[j].z, bb[j].z);
            xd[(nh + j * 4 + 3) * (XS2 / 2) + cp] = pk2(a[j].w, bb[j].w);
        }
    }
    __syncthreads();

    const int w  = t >> 6;
    const int l  = t & 63;
    const int lm = l & 15;
    const int q  = l >> 4;
    const int nc = w & 1;
    const int gh = w >> 1;
    const int n  = n0 + nc * 16 + lm;    // this lane's output column

    // ---- B-frags from xs: lane (q,lm): x[c = kc*32+q*8+j][n-row nc*16+lm] ----
    short8 bf[8];
    const unsigned short* xrow = xs + (nc * 16 + lm) * XS2 + q * 8;
    if (gh == 0) {
#pragma unroll
        for (int kc = 0; kc < 8; kc++)
            bf[kc] = *reinterpret_cast<const short8*>(xrow + kc * 32);
    } else {
#pragma unroll
        for (int kc = 4; kc < 8; kc++)
            bf[kc] = *reinterpret_cast<const short8*>(xrow + kc * 32);
    }

    // ---- proj (gh==0): D[o 16][n 16] over full C ----
    if (gh == 0) {
        f32x4 pa = {0.f, 0.f, 0.f, 0.f};
        const unsigned short* wr = wqk + lm * C_ + q * 8;
#pragma unroll
        for (int kc = 0; kc < 8; kc++) {
            const short8 af = *reinterpret_cast<const short8*>(wr + kc * 32);
            pa = MFMA16(af, bf[kc], pa);
        }
        // lane (q,lm): rows o = q*4+r, col n
        if (q < 2) {
            const int o = q * 4;
            uint2 p;
            p.x = pk2(pa[0] + bq[o + 0] * LOG2E, pa[1] + bq[o + 1] * LOG2E);
            p.y = pk2(pa[2] + bq[o + 2] * LOG2E, pa[3] + bq[o + 3] * LOG2E);
            *reinterpret_cast<uint2*>(wsu + QT_OFF +
                ((size_t)(dq * B_ + b) * N_ + n) * 8 + o) = p;
        } else {
            const int o = (q - 2) * 4;
            uint2 p;
            p.x = pk2(pa[0] + bk[o + 0], pa[1] + bk[o + 1]);
            p.y = pk2(pa[2] + bk[o + 2], pa[3] + bk[o + 3]);
            *reinterpret_cast<uint2*>(wsu + KT_OFF +
                ((size_t)(dk * B_ + b) * N_ + n) * 8 + o) = p;
        }
    }

    // ---- grouped conv: this wave's two groups ----
    unsigned short* vout = wsu + V_OFF + (size_t)(dv * B_ + b) * C_ * N_;
#pragma unroll
    for (int gi = 0; gi < 2; gi++) {
        const int g = gh * 2 + gi;
#pragma unroll
        for (int ocb = 0; ocb < 4; ocb++) {
            f32x4 ca = {0.f, 0.f, 0.f, 0.f};
#pragma unroll
            for (int kc2 = 0; kc2 < 2; kc2++) {
                const short8 af = *reinterpret_cast<const short8*>(
                    wv + (size_t)(g * CG_ + ocb * 16 + lm) * CG_ + kc2 * 32 + q * 8);
                ca = MFMA16(af, bf[g * 2 + kc2], ca);
            }
            const int cb = g * 64 + ocb * 16 + q * 4;
#pragma unroll
            for (int r = 0; r < 4; r++)
                vout[(size_t)(cb + r) * N_ + n] = f2bf(ca[r] + bv[cb + r]);
        }
    }
}

// ---------------------------------------------------------------------------
// Kernel 2: l2z[d][b][n] = -log2( sum_m exp2(s'[n][m]) ).
// grid(256 n-tiles of 16, B, 2), block 256; wave w sums m-quarter w*1024.
// ---------------------------------------------------------------------------
__global__ __launch_bounds__(256) void zcalc(unsigned short* __restrict__ wsu,
                                             float* __restrict__ wsf)
{
    const int d = blockIdx.z;
    const int b = blockIdx.y;
    const int t = threadIdx.x;
    const int w = t >> 6;
    const int l = t & 63;
    const int lm = l & 15;
    const int q  = l >> 4;
    const int n0 = blockIdx.x * 16;

    const unsigned short* qT = wsu + QT_OFF + (size_t)(d * B_ + b) * N_ * 8;
    const unsigned short* kT = wsu + KT_OFF + (size_t)(d * B_ + b) * N_ * 8;

    const short8 z8 = {0, 0, 0, 0, 0, 0, 0, 0};
    const f32x4 zero = {0.f, 0.f, 0.f, 0.f};

    const short8 afrag = (q == 0)
        ? *reinterpret_cast<const short8*>(qT + (size_t)(n0 + lm) * 8) : z8;

    float zacc[4] = {0.f, 0.f, 0.f, 0.f};

    for (int mt = 0; mt < 16; mt++) {
        const int mb = w * 1024 + mt * 64;
#pragma unroll
        for (int kb = 0; kb < 4; kb++) {
            const short8 bk = (q == 0)
                ? *reinterpret_cast<const short8*>(kT + (size_t)(mb + kb * 16 + lm) * 8)
                : z8;
            const f32x4 sv = MFMA16(afrag, bk, zero);
#pragma unroll
            for (int r = 0; r < 4; r++) zacc[r] += EXP2F(sv[r]);
        }
    }

    // reduce across 16 m-lanes
#pragma unroll
    for (int r = 0; r < 4; r++) {
        zacc[r] += __shfl_xor(zacc[r], 1);
        zacc[r] += __shfl_xor(zacc[r], 2);
        zacc[r] += __shfl_xor(zacc[r], 4);
        zacc[r] += __shfl_xor(zacc[r], 8);
    }
    __shared__ float zred[4][16];
    if (lm == 0)
        *reinterpret_cast<float4*>(&zred[w][q * 4]) =
            float4{zacc[0], zacc[1], zacc[2], zacc[3]};
    __syncthreads();
    if (t < 16) {
        const float Z = zred[0][t] + zred[1][t] + zred[2][t] + zred[3][t];
        wsf[L2Z_OFFF + (size_t)(d * B_ + b) * N_ + n0 + t] = -__log2f(Z);
    }
}

// ---------------------------------------------------------------------------
// Kernel 3: out = f + beta * V · E'   — wave-autonomous, NO barriers in loop.
// Block tile 128c x 64m; wave tile 64c x 32m (wc=w&1, wm=w>>1).
// Per kstep (n 64): 8 padded E-MFMAs -> exp2 -> wave-private LDS round-trip
// (C-layout -> B-layout, lgkmcnt-ordered, no __syncthreads) -> 16 main MFMAs.
// A/q/z global loads fully ping-pong double-buffered (never drained: no barriers).
// grid(64 m, 2 c, 4 db) = 512 blocks, 256 thr.
// ---------------------------------------------------------------------------
#define ESTR 72   // private Es row stride (shorts)

__global__ __launch_bounds__(256, 2) void attn_gemm(
    const float* __restrict__ fL, const float* __restrict__ fU,
    const float* __restrict__ betap,
    const unsigned short* __restrict__ wsu,
    const float* __restrict__ wsf,
    float* __restrict__ out)
{
    const int d  = blockIdx.z >> 1;
    const int b  = blockIdx.z & 1;
    const int t  = threadIdx.x;
    const int w  = t >> 6;
    const int l  = t & 63;
    const int lm = l & 15;
    const int q  = l >> 4;
    const int wc = w & 1;
    const int wm = w >> 1;
    const int c0  = blockIdx.y * 128 + wc * 64;
    const int m0w = blockIdx.x * 64 + wm * 32;

    const unsigned short* qT = wsu + QT_OFF + (size_t)(d * B_ + b) * N_ * 8;
    const unsigned short* kT = wsu + KT_OFF + (size_t)(d * B_ + b) * N_ * 8;
    const unsigned short* V  = wsu + V_OFF + (size_t)(d * B_ + b) * C_ * N_;
    const float* l2z = wsf + L2Z_OFFF + (size_t)(d * B_ + b) * N_;
    const float* f = ((d == 0) ? fL : fU) + (size_t)b * C_ * N_;
    float*       o = out + (size_t)(d * B_ + b) * C_ * N_;

    __shared__ unsigned short Es[4][32 * ESTR];
    unsigned short* Esw = Es[w];

    const short8 z8 = {0, 0, 0, 0, 0, 0, 0, 0};

    // persistent k-frags for E-gen (rank-8 real in quad 0)
    short8 kf[2];
#pragma unroll
    for (int mb = 0; mb < 2; mb++)
        kf[mb] = (q == 0)
            ? *reinterpret_cast<const short8*>(kT + (size_t)(m0w + mb * 16 + lm) * 8)
            : z8;

    const unsigned short* Abase = V + (size_t)(c0 + lm) * N_ + q * 8;
    const float* zrow = l2z + q * 4;
    const unsigned short* qrow = qT + (size_t)lm * 8;

    f32x4 acc[4][2];
#pragma unroll
    for (int cb = 0; cb < 4; cb++)
#pragma unroll
        for (int mb = 0; mb < 2; mb++) acc[cb][mb] = f32x4{0.f, 0.f, 0.f, 0.f};

    short8 Av0[8], Av1[8], qA0[4], qA1[4];
    f32x4  cz0[4], cz1[4];

    auto kload = [&](short8* Av, short8* qA, f32x4* cz, int n0) {
#pragma unroll
        for (int cb = 0; cb < 4; cb++)
#pragma unroll
            for (int kc = 0; kc < 2; kc++)
                Av[cb * 2 + kc] = *reinterpret_cast<const short8*>(
                    Abase + (size_t)(cb * 16) * N_ + n0 + kc * 32);
#pragma unroll
        for (int nc = 0; nc < 4; nc++) {
            qA[nc] = (q == 0)
                ? *reinterpret_cast<const short8*>(qrow + (size_t)(n0 + nc * 16) * 8)
                : z8;
            cz[nc] = *reinterpret_cast<const f32x4*>(zrow + n0 + nc * 16);
        }
    };

    auto kstep = [&](short8* Av, short8* qA, f32x4* cz) {
        // E-gen: per m-chunk, 4 n-chunk MFMAs; C=-log2Z folded; exp2; private LDS
#pragma unroll
        for (int mb = 0; mb < 2; mb++) {
#pragma unroll
            for (int ncc = 0; ncc < 4; ncc++) {
                const f32x4 sv = MFMA16(qA[ncc], kf[mb], cz[ncc]);
                uint2 p;
                p.x = pk2(EXP2F(sv[0]), EXP2F(sv[1]));
                p.y = pk2(EXP2F(sv[2]), EXP2F(sv[3]));
                *reinterpret_cast<uint2*>(
                    Esw + (mb * 16 + lm) * ESTR + ncc * 16 + q * 4) = p;
            }
        }
        // B-frags back (same wave: lgkmcnt ordering only, no barrier)
        short8 Bf[2][2];
#pragma unroll
        for (int mb = 0; mb < 2; mb++)
#pragma unroll
            for (int kc = 0; kc < 2; kc++)
                Bf[mb][kc] = *reinterpret_cast<const short8*>(
                    Esw + (mb * 16 + lm) * ESTR + kc * 32 + q * 8);
        // main MFMAs
#pragma unroll
        for (int kc = 0; kc < 2; kc++)
#pragma unroll
            for (int cb = 0; cb < 4; cb++)
#pragma unroll
                for (int mb = 0; mb < 2; mb++)
                    acc[cb][mb] = MFMA16(Av[cb * 2 + kc], Bf[mb][kc], acc[cb][mb]);
    };

    kload(Av0, qA0, cz0, 0);
    for (int i = 0; i < 64; i += 2) {
        kload(Av1, qA1, cz1, (i + 1) * 64);
        kstep(Av0, qA0, cz0);
        kload(Av0, qA0, cz0, (i + 2 < 64) ? (i + 2) * 64 : 0);
        kstep(Av1, qA1, cz1);
    }

    // epilogue: out = f + beta * acc
    const float beta = *betap;
#pragma unroll
    for (int cb = 0; cb < 4; cb++) {
#pragma unroll
        for (int mb = 0; mb < 2; mb++) {
            const int c = c0 + cb * 16 + q * 4;
            const int m = m0w + mb * 16 + lm;
#pragma unroll
            for (int r = 0; r < 4; r++) {
                const size_t off = (size_t)(c + r) * N_ + m;
                o[off] = f[off] + beta * acc[cb][mb][r];
            }
        }
    }
}

// ---------------------------------------------------------------------------
extern "C" void kernel_launch(void* const* d_in, const int* in_sizes, int n_in,
                              void* d_out, int out_size, void* d_ws, size_t ws_size,
                              hipStream_t stream)
{
    const float* fL   = (const float*)d_in[0];
    const float* fU   = (const float*)d_in[1];
    const float* qL_w = (const float*)d_in[2];
    const float* qL_b = (const float*)d_in[3];
    const float* kU_w = (const float*)d_in[4];
    const float* kU_b = (const float*)d_in[5];
    const float* vU_w = (const float*)d_in[6];
    const float* vU_b = (const float*)d_in[7];
    const float* qU_w = (const float*)d_in[8];
    const float* qU_b = (const float*)d_in[9];
    const float* kL_w = (const float*)d_in[10];
    const float* kL_b = (const float*)d_in[11];
    const float* vL_w = (const float*)d_in[12];
    const float* vL_b = (const float*)d_in[13];
    const float* beta = (const float*)d_in[14];

    unsigned short* wsu = (unsigned short*)d_ws;
    float*          wsf = (float*)d_ws;
    float*          outf = (float*)d_out;

    wpack<<<dim3(2), 256, 0, stream>>>(qL_w, kL_w, vL_w, qU_w, kU_w, vU_w, wsu);

    fused_pre<<<dim3(128, 1, 4), 256, 0, stream>>>(
        fL, fU, qL_b, kL_b, vL_b, qU_b, kU_b, vU_b, wsu);

    zcalc<<<dim3(256, B_, 2), 256, 0, stream>>>(wsu, wsf);

    attn_gemm<<<dim3(64, 2, 4), 256, 0, stream>>>(
        fL, fU, beta, wsu, wsf, outf);
}

// Round 5
// 216.741 us; speedup vs baseline: 1.3636x; 1.3636x over previous
//
#include <hip/hip_runtime.h>
#include <hip/hip_bf16.h>

// Problem dims
#define B_  2
#define C_  256
#define N_  4096
#define R_  8
#define G_  4
#define CG_ 64

typedef __attribute__((ext_vector_type(8))) short short8;
typedef __attribute__((ext_vector_type(4))) float f32x4;

#define MFMA16(a, b, c) __builtin_amdgcn_mfma_f32_16x16x32_bf16((a), (b), (c), 0, 0, 0)
#define EXP2F(x) __builtin_amdgcn_exp2f(x)
#define LOG2E 1.44269504088896f

__device__ inline unsigned int pk2(float a, float b) {
    union { __hip_bfloat162 h; unsigned int u; } cv;
    cv.h = __float22bfloat162_rn(float2{a, b});
    return cv.u;
}
__device__ inline unsigned short f2bf(float f) {
    union { __hip_bfloat16 h; unsigned short u; } cv;
    cv.h = __float2bfloat16(f);
    return cv.u;
}
__device__ inline float bf2f(unsigned short h) {
    union { unsigned int u; float f; } v; v.u = ((unsigned int)h) << 16;
    return v.f;
}

// Workspace layout (ushort units). ALL hot-loop data is stored in MFMA
// fragment order: [tile][lane 64][8 bf16] -> every load is a coalesced
// 1KB global_load_dwordx4 (lane-contiguous), never a 16-row scatter.
//  qF [db 4][nt 256][64][8]  q-frags (log2e folded, quads>=1 zero)
//  kF [db 4][mt 256][64][8]  k-frags (quads>=1 zero)
//  VF [db 4][ct 16][nc 128][64][8]  V A-frags (zcalc rescales by Zinv in place)
//  wqkF [s 2][kc 8][64][8]   proj weight A-frags (q rows pre-scaled log2e)
//  wvF  [s 2][g 4][ocb 4][kc2 2][64][8]  conv weight A-frags
#define QF_OFF    0
#define KF_OFF    524288
#define VF_OFF    1048576
#define WQKF_OFF  5242880
#define WVF_OFF   5251072
// end 5283840 ushorts = 10.6 MB

// ---------------------------------------------------------------------------
// Kernel 0: pack + swizzle weights into fragment order. grid(2) -> s.
// ---------------------------------------------------------------------------
__global__ __launch_bounds__(256) void wpack(
    const float* __restrict__ qLw, const float* __restrict__ kLw,
    const float* __restrict__ vLw,
    const float* __restrict__ qUw, const float* __restrict__ kUw,
    const float* __restrict__ vUw,
    unsigned short* __restrict__ wsu)
{
    const int s = blockIdx.x;
    const float* wq = s ? qUw : qLw;
    const float* wk = s ? kUw : kLw;
    const float* wv = s ? vUw : vLw;

    // wqkF: A[row=o=lane&15][k = kc*32 + (lane>>4)*8 + j]
    for (int i = threadIdx.x; i < 8 * 512; i += 256) {
        const int kc = i >> 9, l = (i >> 3) & 63, j = i & 7;
        const int o = l & 15, c = kc * 32 + (l >> 4) * 8 + j;
        const float v = (o < 8) ? wq[o * C_ + c] * LOG2E : wk[(o - 8) * C_ + c];
        wsu[WQKF_OFF + s * 4096 + i] = f2bf(v);
    }
    // wvF: A[row=oc_local=lane&15][k = kc2*32 + (lane>>4)*8 + j]
    for (int i = threadIdx.x; i < 16384; i += 256) {
        const int g = i >> 12, r1 = i & 4095;
        const int ocb = r1 >> 10, r2 = r1 & 1023;
        const int kc2 = r2 >> 9, l = (r2 >> 3) & 63, j = r2 & 7;
        const int oc = ocb * 16 + (l & 15), ic = kc2 * 32 + (l >> 4) * 8 + j;
        wsu[WVF_OFF + s * 16384 + i] = f2bf(wv[g * (CG_ * CG_) + oc * CG_ + ic]);
    }
}

// ---------------------------------------------------------------------------
// Kernel 1: fused proj + grouped conv -> frag-swizzled qF/kF/VF.
// grid(128 n-strips of 32, 1, 4 z=s*2+b), block 256 (4 waves).
// Waves: ncl=w&1 (n 16-half), gh=w>>1. gh0: proj + groups 0,1; gh1: g2,3.
// ---------------------------------------------------------------------------
#define XS2 264   // xs row stride (shorts)

__global__ __launch_bounds__(256) void fused_pre(
    const float* __restrict__ fL, const float* __restrict__ fU,
    const float* __restrict__ qLb, const float* __restrict__ kLb,
    const float* __restrict__ vLb,
    const float* __restrict__ qUb, const float* __restrict__ kUb,
    const float* __restrict__ vUb,
    unsigned short* __restrict__ wsu)
{
    const int s   = blockIdx.z >> 1;
    const int b   = blockIdx.z & 1;
    const int nc0 = blockIdx.x;        // 32-n strip index
    const int n0  = nc0 * 32;
    const int t   = threadIdx.x;

    const float* x  = (s ? fU : fL) + (size_t)b * C_ * N_;
    const float* bq = s ? qUb : qLb;
    const float* bk = s ? kUb : kLb;
    const float* bv = s ? vUb : vLb;
    const int dq = s, dk = 1 - s, dv = 1 - s;

    __shared__ __align__(16) unsigned short xs[32 * XS2];   // [n 32][c 256]
    __shared__ __align__(16) unsigned short vtmp[256 * 48]; // [c 256][n 32], stride 48
    __shared__ __align__(16) float qtmp[2][16][17];

    // ---- stage x (fp32 [c][n]) -> xs (bf16 [n][c]) ----
    {
        const int cp = t >> 1;          // c-pair 0..127
        const int nh = (t & 1) * 16;    // n-half
        const float* r0 = x + (size_t)(2 * cp) * N_ + n0 + nh;
        const float* r1 = r0 + N_;
        float4 a[4], bb[4];
#pragma unroll
        for (int j = 0; j < 4; j++) {
            a[j]  = *reinterpret_cast<const float4*>(r0 + j * 4);
            bb[j] = *reinterpret_cast<const float4*>(r1 + j * 4);
        }
        unsigned int* xd = reinterpret_cast<unsigned int*>(xs);
#pragma unroll
        for (int j = 0; j < 4; j++) {
            xd[(nh + j * 4 + 0) * (XS2 / 2) + cp] = pk2(a[j].x, bb[j].x);
            xd[(nh + j * 4 + 1) * (XS2 / 2) + cp] = pk2(a[j].y, bb[j].y);
            xd[(nh + j * 4 + 2) * (XS2 / 2) + cp] = pk2(a[j].z, bb[j].z);
            xd[(nh + j * 4 + 3) * (XS2 / 2) + cp] = pk2(a[j].w, bb[j].w);
        }
    }
    __syncthreads();

    const int w  = t >> 6;
    const int l  = t & 63;
    const int lm = l & 15;
    const int q  = l >> 4;
    const int ncl = w & 1;
    const int gh  = w >> 1;

    // ---- B-frags: B[col=n=lm][k=c=kc*32+q*8+j] from xs ----
    short8 bf[8];
    const unsigned short* xrow = xs + (ncl * 16 + lm) * XS2 + q * 8;
    if (gh == 0) {
#pragma unroll
        for (int kc = 0; kc < 8; kc++)
            bf[kc] = *reinterpret_cast<const short8*>(xrow + kc * 32);
    } else {
#pragma unroll
        for (int kc = 4; kc < 8; kc++)
            bf[kc] = *reinterpret_cast<const short8*>(xrow + kc * 32);
    }

    // ---- proj (gh==0 waves): 16 rows (0-7 q-scaled, 8-15 k) x 16 n ----
    if (gh == 0) {
        const unsigned short* wb = wsu + WQKF_OFF + s * 4096;
        f32x4 pa = {0.f, 0.f, 0.f, 0.f};
#pragma unroll
        for (int kc = 0; kc < 8; kc++) {
            const short8 af = *reinterpret_cast<const short8*>(wb + kc * 512 + l * 8);
            pa = MFMA16(af, bf[kc], pa);
        }
        // bias (q rows scaled by log2e), transpose via same-wave LDS bounce
#pragma unroll
        for (int r = 0; r < 4; r++) {
            const int o = q * 4 + r;
            const float v = pa[r] + ((q < 2) ? bq[o] * LOG2E : bk[o - 8]);
            qtmp[w][o][lm] = v;
        }
        const int nt = nc0 * 2 + w;      // 16-n tile index
        uint4 pq = {0u, 0u, 0u, 0u}, pk = {0u, 0u, 0u, 0u};
        if (q == 0) {
            float aq[8], ak[8];
#pragma unroll
            for (int o2 = 0; o2 < 8; o2++) { aq[o2] = qtmp[w][o2][lm]; ak[o2] = qtmp[w][8 + o2][lm]; }
            pq.x = pk2(aq[0], aq[1]); pq.y = pk2(aq[2], aq[3]);
            pq.z = pk2(aq[4], aq[5]); pq.w = pk2(aq[6], aq[7]);
            pk.x = pk2(ak[0], ak[1]); pk.y = pk2(ak[2], ak[3]);
            pk.z = pk2(ak[4], ak[5]); pk.w = pk2(ak[6], ak[7]);
        }
        *reinterpret_cast<uint4*>(wsu + QF_OFF + ((size_t)(dq * B_ + b) * 256 + nt) * 512 + l * 8) = pq;
        *reinterpret_cast<uint4*>(wsu + KF_OFF + ((size_t)(dk * B_ + b) * 256 + nt) * 512 + l * 8) = pk;
    }

    // ---- grouped conv: this wave's two groups -> vtmp [c][n] ----
    {
        const unsigned short* vb = wsu + WVF_OFF + s * 16384;
#pragma unroll
        for (int gi = 0; gi < 2; gi++) {
            const int g = gh * 2 + gi;
#pragma unroll
            for (int ocb = 0; ocb < 4; ocb++) {
                f32x4 ca = {0.f, 0.f, 0.f, 0.f};
#pragma unroll
                for (int kc2 = 0; kc2 < 2; kc2++) {
                    const short8 af = *reinterpret_cast<const short8*>(
                        vb + (((g * 4 + ocb) * 2 + kc2) * 512) + l * 8);
                    ca = MFMA16(af, bf[g * 2 + kc2], ca);
                }
#pragma unroll
                for (int r = 0; r < 4; r++) {
                    const int c = g * 64 + ocb * 16 + q * 4 + r;
                    vtmp[c * 48 + ncl * 16 + lm] = f2bf(ca[r] + bv[c]);
                }
            }
        }
    }
    __syncthreads();

    // ---- emit VF frags: A[row=c_local=lm][k=n_local=q*8+j], coalesced store ----
    {
        const int db = dv * B_ + b;
#pragma unroll
        for (int ctl = 0; ctl < 4; ctl++) {
            const int ct = w * 4 + ctl;
            const uint4 v4 = *reinterpret_cast<const uint4*>(vtmp + (ct * 16 + lm) * 48 + q * 8);
            *reinterpret_cast<uint4*>(
                wsu + VF_OFF + ((size_t)(db * 16 + ct) * 128 + nc0) * 512 + l * 8) = v4;
        }
    }
}

// ---------------------------------------------------------------------------
// Kernel 2: Z per n-row (rank-8 MFMA sweep over all m), then rescale VF
// in place by Zinv. grid(128 n-strips of 32, B, 2), block 256.
// Wave w sums m-quarter w*64 tiles... (w*64..w*64+63 of 256 mt).
// ---------------------------------------------------------------------------
__global__ __launch_bounds__(256) void zcalc(unsigned short* __restrict__ wsu)
{
    const int d   = blockIdx.z;
    const int b   = blockIdx.y;
    const int nc0 = blockIdx.x;
    const int db  = d * B_ + b;
    const int t   = threadIdx.x;
    const int w   = t >> 6;
    const int l   = t & 63;
    const int lm  = l & 15;
    const int q   = l >> 4;

    const unsigned short* qF = wsu + QF_OFF + (size_t)db * 256 * 512;
    const unsigned short* kF = wsu + KF_OFF + (size_t)db * 256 * 512;

    const short8 qf0 = *reinterpret_cast<const short8*>(qF + (size_t)(nc0 * 2 + 0) * 512 + l * 8);
    const short8 qf1 = *reinterpret_cast<const short8*>(qF + (size_t)(nc0 * 2 + 1) * 512 + l * 8);

    const f32x4 zero = {0.f, 0.f, 0.f, 0.f};
    float za0[4] = {0.f, 0.f, 0.f, 0.f};
    float za1[4] = {0.f, 0.f, 0.f, 0.f};

    short8 kc_ = *reinterpret_cast<const short8*>(kF + (size_t)(w * 64) * 512 + l * 8);
    for (int it = 0; it < 64; it++) {
        const int nmt = w * 64 + ((it + 1) & 63);
        const short8 kn = *reinterpret_cast<const short8*>(kF + (size_t)nmt * 512 + l * 8);
        const f32x4 s0 = MFMA16(qf0, kc_, zero);
        const f32x4 s1 = MFMA16(qf1, kc_, zero);
#pragma unroll
        for (int r = 0; r < 4; r++) { za0[r] += EXP2F(s0[r]); za1[r] += EXP2F(s1[r]); }
        kc_ = kn;
    }

#pragma unroll
    for (int r = 0; r < 4; r++) {
        za0[r] += __shfl_xor(za0[r], 1); za0[r] += __shfl_xor(za0[r], 2);
        za0[r] += __shfl_xor(za0[r], 4); za0[r] += __shfl_xor(za0[r], 8);
        za1[r] += __shfl_xor(za1[r], 1); za1[r] += __shfl_xor(za1[r], 2);
        za1[r] += __shfl_xor(za1[r], 4); za1[r] += __shfl_xor(za1[r], 8);
    }

    __shared__ __align__(16) float zred[4][2][16];
    __shared__ float zs[32];
    if (lm == 0) {
        *reinterpret_cast<float4*>(&zred[w][0][q * 4]) = float4{za0[0], za0[1], za0[2], za0[3]};
        *reinterpret_cast<float4*>(&zred[w][1][q * 4]) = float4{za1[0], za1[1], za1[2], za1[3]};
    }
    __syncthreads();
    if (t < 32) {
        const int tl = t >> 4, idx = t & 15;
        const float Z = zred[0][tl][idx] + zred[1][tl][idx] + zred[2][tl][idx] + zred[3][tl][idx];
        zs[t] = 1.0f / Z;
    }
    __syncthreads();

    // rescale VF[db][*][nc0] in place: lane's 8 elements are n_local = q*8+j
    float zv[8];
#pragma unroll
    for (int j = 0; j < 8; j++) zv[j] = zs[q * 8 + j];
#pragma unroll
    for (int ctl = 0; ctl < 4; ctl++) {
        const int ct = w * 4 + ctl;
        unsigned short* p = wsu + VF_OFF + ((size_t)(db * 16 + ct) * 128 + nc0) * 512 + l * 8;
        union { uint4 v; unsigned short u[8]; } cv;
        cv.v = *reinterpret_cast<const uint4*>(p);
#pragma unroll
        for (int j = 0; j < 8; j++) cv.u[j] = f2bf(bf2f(cv.u[j]) * zv[j]);
        *reinterpret_cast<uint4*>(p) = cv.v;
    }
}

// ---------------------------------------------------------------------------
// Kernel 3: out = f + beta * Vz · E,  E = exp2(q^T k) regenerated per kstep.
// Wave-autonomous (no barriers), all global loads lane-contiguous 1KB frags,
// E double-buffered through wave-private LDS, A/q prefetched 1-2 ksteps ahead.
// Block 256 thr, tile 128c x 64m; wave 64c x 32m. grid(64,2,4)=512, 2 blk/CU.
// ---------------------------------------------------------------------------
__global__ __launch_bounds__(256) void attn_gemm(
    const float* __restrict__ fL, const float* __restrict__ fU,
    const float* __restrict__ betap,
    const unsigned short* __restrict__ wsu,
    float* __restrict__ out)
{
    const int d  = blockIdx.z >> 1;
    const int b  = blockIdx.z & 1;
    const int db = d * B_ + b;
    const int t  = threadIdx.x;
    const int w  = t >> 6;
    const int l  = t & 63;
    const int lm = l & 15;
    const int q  = l >> 4;
    const int wc = w & 1;
    const int wm = w >> 1;
    const int c0w = blockIdx.y * 128 + wc * 64;
    const int m0w = blockIdx.x * 64 + wm * 32;

    const unsigned short* qF = wsu + QF_OFF + (size_t)db * 256 * 512;
    const unsigned short* kF = wsu + KF_OFF + (size_t)db * 256 * 512;
    const unsigned short* VF = wsu + VF_OFF;
    const float* f = ((d == 0) ? fL : fU) + (size_t)b * C_ * N_;
    float*       o = out + (size_t)db * C_ * N_;

    __shared__ __align__(16) unsigned short Es[4][2][32 * 72];
    unsigned short* E0 = Es[w][0];
    unsigned short* E1 = Es[w][1];

    // persistent k-frags for this wave's 32 m (zero quads baked in kF)
    short8 kf[2];
#pragma unroll
    for (int mb = 0; mb < 2; mb++)
        kf[mb] = *reinterpret_cast<const short8*>(
            kF + (size_t)(blockIdx.x * 4 + wm * 2 + mb) * 512 + l * 8);

    // A-frag row bases (coalesced: uniform base + l*8)
    const unsigned short* Ab[4];
#pragma unroll
    for (int cb = 0; cb < 4; cb++)
        Ab[cb] = VF + (size_t)(db * 16 + (c0w >> 4) + cb) * 128 * 512 + l * 8;

    f32x4 acc[4][2];
#pragma unroll
    for (int cb = 0; cb < 4; cb++)
#pragma unroll
        for (int mb = 0; mb < 2; mb++) acc[cb][mb] = f32x4{0.f, 0.f, 0.f, 0.f};

    const f32x4 zero = {0.f, 0.f, 0.f, 0.f};

    short8 A0[8], A1[8], q0[4], q1[4];

    auto loadA = [&](short8* A, int i) {
        const int ncb = (i & 63) * 2;
#pragma unroll
        for (int cb = 0; cb < 4; cb++)
#pragma unroll
            for (int kc = 0; kc < 2; kc++)
                A[cb * 2 + kc] = *reinterpret_cast<const short8*>(Ab[cb] + (size_t)(ncb + kc) * 512);
    };
    auto loadQ = [&](short8* qA, int i) {
        const int ntb = (i & 63) * 4;
#pragma unroll
        for (int nc = 0; nc < 4; nc++)
            qA[nc] = *reinterpret_cast<const short8*>(qF + (size_t)(ntb + nc) * 512 + l * 8);
    };
    auto egen = [&](const short8* qA, unsigned short* Ed) {
#pragma unroll
        for (int mb = 0; mb < 2; mb++)
#pragma unroll
            for (int nc = 0; nc < 4; nc++) {
                const f32x4 sv = MFMA16(qA[nc], kf[mb], zero);
                uint2 p;
                p.x = pk2(EXP2F(sv[0]), EXP2F(sv[1]));
                p.y = pk2(EXP2F(sv[2]), EXP2F(sv[3]));
                *reinterpret_cast<uint2*>(Ed + (mb * 16 + lm) * 72 + nc * 16 + q * 4) = p;
            }
    };
    auto mainm = [&](const short8* A, const unsigned short* Ed) {
        short8 Bf[2][2];
#pragma unroll
        for (int mb = 0; mb < 2; mb++)
#pragma unroll
            for (int kc = 0; kc < 2; kc++)
                Bf[mb][kc] = *reinterpret_cast<const short8*>(
                    Ed + (mb * 16 + lm) * 72 + kc * 32 + q * 8);
#pragma unroll
        for (int kc = 0; kc < 2; kc++)
#pragma unroll
            for (int cb = 0; cb < 4; cb++)
#pragma unroll
                for (int mb = 0; mb < 2; mb++)
                    acc[cb][mb] = MFMA16(A[cb * 2 + kc], Bf[mb][kc], acc[cb][mb]);
    };

    loadA(A0, 0); loadA(A1, 1);
    loadQ(q0, 0); loadQ(q1, 1);
    egen(q0, E0);   // E(0)

    for (int i = 0; i < 64; i += 2) {
        // slot 0: consume E(i)/A(i); generate E(i+1)
        loadQ(q0, i + 2);
        egen(q1, E1);
        mainm(A0, E0);
        loadA(A0, i + 2);
        // slot 1: consume E(i+1)/A(i+1); generate E(i+2)
        loadQ(q1, i + 3);
        egen(q0, E0);
        mainm(A1, E1);
        loadA(A1, i + 3);
    }

    // epilogue: out = f + beta * acc   (D: col m = lm, rows c = q*4+r)
    const float beta = *betap;
#pragma unroll
    for (int cb = 0; cb < 4; cb++) {
#pragma unroll
        for (int mb = 0; mb < 2; mb++) {
            const int c = c0w + cb * 16 + q * 4;
            const int m = m0w + mb * 16 + lm;
#pragma unroll
            for (int r = 0; r < 4; r++) {
                const size_t off = (size_t)(c + r) * N_ + m;
                o[off] = f[off] + beta * acc[cb][mb][r];
            }
        }
    }
}

// ---------------------------------------------------------------------------
extern "C" void kernel_launch(void* const* d_in, const int* in_sizes, int n_in,
                              void* d_out, int out_size, void* d_ws, size_t ws_size,
                              hipStream_t stream)
{
    const float* fL   = (const float*)d_in[0];
    const float* fU   = (const float*)d_in[1];
    const float* qL_w = (const float*)d_in[2];
    const float* qL_b = (const float*)d_in[3];
    const float* kU_w = (const float*)d_in[4];
    const float* kU_b = (const float*)d_in[5];
    const float* vU_w = (const float*)d_in[6];
    const float* vU_b = (const float*)d_in[7];
    const float* qU_w = (const float*)d_in[8];
    const float* qU_b = (const float*)d_in[9];
    const float* kL_w = (const float*)d_in[10];
    const float* kL_b = (const float*)d_in[11];
    const float* vL_w = (const float*)d_in[12];
    const float* vL_b = (const float*)d_in[13];
    const float* beta = (const float*)d_in[14];

    unsigned short* wsu  = (unsigned short*)d_ws;
    float*          outf = (float*)d_out;

    wpack<<<dim3(2), 256, 0, stream>>>(qL_w, kL_w, vL_w, qU_w, kU_w, vU_w, wsu);

    fused_pre<<<dim3(128, 1, 4), 256, 0, stream>>>(
        fL, fU, qL_b, kL_b, vL_b, qU_b, kU_b, vU_b, wsu);

    zcalc<<<dim3(128, B_, 2), 256, 0, stream>>>(wsu);

    attn_gemm<<<dim3(64, 2, 4), 256, 0, stream>>>(
        fL, fU, beta, wsu, outf);
}

// Round 6
// 191.279 us; speedup vs baseline: 1.5451x; 1.1331x over previous
//
#include <hip/hip_runtime.h>
#include <hip/hip_bf16.h>

// Problem dims
#define B_  2
#define C_  256
#define N_  4096
#define R_  8
#define G_  4
#define CG_ 64

typedef __attribute__((ext_vector_type(8))) short short8;
typedef __attribute__((ext_vector_type(4))) float f32x4;

#define MFMA16(a, b, c) __builtin_amdgcn_mfma_f32_16x16x32_bf16((a), (b), (c), 0, 0, 0)
#define EXP2F(x) __builtin_amdgcn_exp2f(x)
#define LOG2E 1.44269504088896f

__device__ inline unsigned int pk2(float a, float b) {
    union { __hip_bfloat162 h; unsigned int u; } cv;
    cv.h = __float22bfloat162_rn(float2{a, b});
    return cv.u;
}
__device__ inline unsigned short f2bf(float f) {
    union { __hip_bfloat16 h; unsigned short u; } cv;
    cv.h = __float2bfloat16(f);
    return cv.u;
}

// Workspace (ushort units unless noted). All hot data in MFMA fragment order
// [tile][lane 64][8 bf16] -> every load is a coalesced 1KB dwordx4.
//  qF  [db 4][nt 256][64][8]  (log2e folded; lanes>=16 zero)
//  kF  [db 4][mt 256][64][8]  (lanes>=16 zero)
//  VF  [db 4][ct 16][nc 128][64][8]  plain V (bias applied, no Z)
//  l2z f32 [db 4][n 4096] = -log2(Z)
#define QF_OFF   0
#define KF_OFF   524288
#define VF_OFF   1048576
#define L2Z_OFFF 2621440        // float index (byte 10485760)
// total bytes: 10551296 (~10.6 MB)

// ---------------------------------------------------------------------------
// Kernel 1: fused proj + grouped conv -> frag-swizzled qF/kF/VF.
// Weights packed inline from fp32 (no separate wpack kernel).
// grid(128 n-strips of 32, 1, 4 z=s*2+b), block 256 (4 waves).
// Waves: ncl=w&1 (n 16-half), gh=w>>1. gh0: proj + groups 0,1; gh1: g2,3.
// ---------------------------------------------------------------------------
#define XS2 264   // xs row stride (shorts)

__global__ __launch_bounds__(256) void fused_pre(
    const float* __restrict__ fL, const float* __restrict__ fU,
    const float* __restrict__ qLw, const float* __restrict__ qLb,
    const float* __restrict__ kLw, const float* __restrict__ kLb,
    const float* __restrict__ vLw, const float* __restrict__ vLb,
    const float* __restrict__ qUw, const float* __restrict__ qUb,
    const float* __restrict__ kUw, const float* __restrict__ kUb,
    const float* __restrict__ vUw, const float* __restrict__ vUb,
    unsigned short* __restrict__ wsu)
{
    const int s   = blockIdx.z >> 1;
    const int b   = blockIdx.z & 1;
    const int nc0 = blockIdx.x;        // 32-n strip index
    const int n0  = nc0 * 32;
    const int t   = threadIdx.x;

    const float* x  = (s ? fU : fL) + (size_t)b * C_ * N_;
    const float* wq = s ? qUw : qLw;
    const float* bq = s ? qUb : qLb;
    const float* wk = s ? kUw : kLw;
    const float* bk = s ? kUb : kLb;
    const float* wv = s ? vUw : vLw;
    const float* bv = s ? vUb : vLb;
    const int dq = s, dk = 1 - s, dv = 1 - s;

    __shared__ __align__(16) unsigned short xs[32 * XS2];   // [n 32][c 256]
    __shared__ __align__(16) unsigned short vtmp[256 * 48]; // [c 256][n 32]
    __shared__ __align__(16) float qtmp[2][16][17];

    // ---- stage x (fp32 [c][n]) -> xs (bf16 [n][c]) ----
    {
        const int cp = t >> 1;          // c-pair 0..127
        const int nh = (t & 1) * 16;    // n-half
        const float* r0 = x + (size_t)(2 * cp) * N_ + n0 + nh;
        const float* r1 = r0 + N_;
        float4 a[4], bb[4];
#pragma unroll
        for (int j = 0; j < 4; j++) {
            a[j]  = *reinterpret_cast<const float4*>(r0 + j * 4);
            bb[j] = *reinterpret_cast<const float4*>(r1 + j * 4);
        }
        unsigned int* xd = reinterpret_cast<unsigned int*>(xs);
#pragma unroll
        for (int j = 0; j < 4; j++) {
            xd[(nh + j * 4 + 0) * (XS2 / 2) + cp] = pk2(a[j].x, bb[j].x);
            xd[(nh + j * 4 + 1) * (XS2 / 2) + cp] = pk2(a[j].y, bb[j].y);
            xd[(nh + j * 4 + 2) * (XS2 / 2) + cp] = pk2(a[j].z, bb[j].z);
            xd[(nh + j * 4 + 3) * (XS2 / 2) + cp] = pk2(a[j].w, bb[j].w);
        }
    }
    __syncthreads();

    const int w  = t >> 6;
    const int l  = t & 63;
    const int lm = l & 15;
    const int q  = l >> 4;
    const int ncl = w & 1;
    const int gh  = w >> 1;

    // ---- B-frags: B[col=n=lm][k=c=kc*32+q*8+j] from xs ----
    short8 bf[8];
    const unsigned short* xrow = xs + (ncl * 16 + lm) * XS2 + q * 8;
    if (gh == 0) {
#pragma unroll
        for (int kc = 0; kc < 8; kc++)
            bf[kc] = *reinterpret_cast<const short8*>(xrow + kc * 32);
    } else {
#pragma unroll
        for (int kc = 4; kc < 8; kc++)
            bf[kc] = *reinterpret_cast<const short8*>(xrow + kc * 32);
    }

    // ---- proj (gh==0 waves): rows 0-7 q (log2e-scaled), 8-15 k ----
    if (gh == 0) {
        const int o = lm;
        const float* wrow = (o < 8) ? (wq + o * C_) : (wk + (o - 8) * C_);
        const float scl = (o < 8) ? LOG2E : 1.0f;
        f32x4 pa = {0.f, 0.f, 0.f, 0.f};
#pragma unroll
        for (int kc = 0; kc < 8; kc++) {
            const float4 w0 = *reinterpret_cast<const float4*>(wrow + kc * 32 + q * 8);
            const float4 w1 = *reinterpret_cast<const float4*>(wrow + kc * 32 + q * 8 + 4);
            union { unsigned int u[4]; short8 v; } aw;
            aw.u[0] = pk2(w0.x * scl, w0.y * scl);
            aw.u[1] = pk2(w0.z * scl, w0.w * scl);
            aw.u[2] = pk2(w1.x * scl, w1.y * scl);
            aw.u[3] = pk2(w1.z * scl, w1.w * scl);
            pa = MFMA16(aw.v, bf[kc], pa);
        }
        // bias, transpose via same-wave LDS bounce, frag-order store
#pragma unroll
        for (int r = 0; r < 4; r++) {
            const int oo = q * 4 + r;
            const float v = pa[r] + ((q < 2) ? bq[oo] * LOG2E : bk[oo - 8]);
            qtmp[w][oo][lm] = v;
        }
        const int nt = nc0 * 2 + w;      // 16-n tile index
        uint4 pq = {0u, 0u, 0u, 0u}, pk = {0u, 0u, 0u, 0u};
        if (q == 0) {
            float aq[8], ak[8];
#pragma unroll
            for (int o2 = 0; o2 < 8; o2++) { aq[o2] = qtmp[w][o2][lm]; ak[o2] = qtmp[w][8 + o2][lm]; }
            pq.x = pk2(aq[0], aq[1]); pq.y = pk2(aq[2], aq[3]);
            pq.z = pk2(aq[4], aq[5]); pq.w = pk2(aq[6], aq[7]);
            pk.x = pk2(ak[0], ak[1]); pk.y = pk2(ak[2], ak[3]);
            pk.z = pk2(ak[4], ak[5]); pk.w = pk2(ak[6], ak[7]);
        }
        *reinterpret_cast<uint4*>(wsu + QF_OFF + ((size_t)(dq * B_ + b) * 256 + nt) * 512 + l * 8) = pq;
        *reinterpret_cast<uint4*>(wsu + KF_OFF + ((size_t)(dk * B_ + b) * 256 + nt) * 512 + l * 8) = pk;
    }

    // ---- grouped conv: this wave's two groups -> vtmp [c][n] ----
    {
#pragma unroll
        for (int gi = 0; gi < 2; gi++) {
            const int g = gh * 2 + gi;
#pragma unroll
            for (int ocb = 0; ocb < 4; ocb++) {
                f32x4 ca = {0.f, 0.f, 0.f, 0.f};
#pragma unroll
                for (int kc2 = 0; kc2 < 2; kc2++) {
                    const float* wr = wv + (size_t)g * (CG_ * CG_)
                                    + (ocb * 16 + lm) * CG_ + kc2 * 32 + q * 8;
                    const float4 w0 = *reinterpret_cast<const float4*>(wr);
                    const float4 w1 = *reinterpret_cast<const float4*>(wr + 4);
                    union { unsigned int u[4]; short8 v; } aw;
                    aw.u[0] = pk2(w0.x, w0.y); aw.u[1] = pk2(w0.z, w0.w);
                    aw.u[2] = pk2(w1.x, w1.y); aw.u[3] = pk2(w1.z, w1.w);
                    ca = MFMA16(aw.v, bf[g * 2 + kc2], ca);
                }
#pragma unroll
                for (int r = 0; r < 4; r++) {
                    const int c = g * 64 + ocb * 16 + q * 4 + r;
                    vtmp[c * 48 + ncl * 16 + lm] = f2bf(ca[r] + bv[c]);
                }
            }
        }
    }
    __syncthreads();

    // ---- emit VF frags: A[row=c_local=lm][k=n_local=q*8+j], coalesced ----
    {
        const int db = dv * B_ + b;
#pragma unroll
        for (int ctl = 0; ctl < 4; ctl++) {
            const int ct = w * 4 + ctl;
            const uint4 v4 = *reinterpret_cast<const uint4*>(vtmp + (ct * 16 + lm) * 48 + q * 8);
            *reinterpret_cast<uint4*>(
                wsu + VF_OFF + ((size_t)(db * 16 + ct) * 128 + nc0) * 512 + l * 8) = v4;
        }
    }
}

// ---------------------------------------------------------------------------
// Kernel 2: l2z[db][n] = -log2( sum_m exp2(s'[n][m]) ), rank-8 padded MFMA.
// grid(128 n-strips of 32, B, 2), block 256; wave w sums m-quarter.
// ---------------------------------------------------------------------------
__global__ __launch_bounds__(256) void zcalc(const unsigned short* __restrict__ wsu,
                                             float* __restrict__ wsf)
{
    const int d   = blockIdx.z;
    const int b   = blockIdx.y;
    const int nc0 = blockIdx.x;
    const int db  = d * B_ + b;
    const int t   = threadIdx.x;
    const int w   = t >> 6;
    const int l   = t & 63;
    const int lm  = l & 15;
    const int q   = l >> 4;

    const unsigned short* qF = wsu + QF_OFF + (size_t)db * 256 * 512;
    const unsigned short* kF = wsu + KF_OFF + (size_t)db * 256 * 512;

    const short8 qf0 = *reinterpret_cast<const short8*>(qF + (size_t)(nc0 * 2 + 0) * 512 + l * 8);
    const short8 qf1 = *reinterpret_cast<const short8*>(qF + (size_t)(nc0 * 2 + 1) * 512 + l * 8);

    const f32x4 zero = {0.f, 0.f, 0.f, 0.f};
    float za0[4] = {0.f, 0.f, 0.f, 0.f};
    float za1[4] = {0.f, 0.f, 0.f, 0.f};

    short8 kc_ = *reinterpret_cast<const short8*>(kF + (size_t)(w * 64) * 512 + l * 8);
    for (int it = 0; it < 64; it++) {
        const int nmt = w * 64 + ((it + 1) & 63);
        const short8 kn = *reinterpret_cast<const short8*>(kF + (size_t)nmt * 512 + l * 8);
        const f32x4 s0 = MFMA16(qf0, kc_, zero);
        const f32x4 s1 = MFMA16(qf1, kc_, zero);
#pragma unroll
        for (int r = 0; r < 4; r++) { za0[r] += EXP2F(s0[r]); za1[r] += EXP2F(s1[r]); }
        kc_ = kn;
    }

#pragma unroll
    for (int r = 0; r < 4; r++) {
        za0[r] += __shfl_xor(za0[r], 1); za0[r] += __shfl_xor(za0[r], 2);
        za0[r] += __shfl_xor(za0[r], 4); za0[r] += __shfl_xor(za0[r], 8);
        za1[r] += __shfl_xor(za1[r], 1); za1[r] += __shfl_xor(za1[r], 2);
        za1[r] += __shfl_xor(za1[r], 4); za1[r] += __shfl_xor(za1[r], 8);
    }

    __shared__ __align__(16) float zred[4][2][16];
    if (lm == 0) {
        *reinterpret_cast<float4*>(&zred[w][0][q * 4]) = float4{za0[0], za0[1], za0[2], za0[3]};
        *reinterpret_cast<float4*>(&zred[w][1][q * 4]) = float4{za1[0], za1[1], za1[2], za1[3]};
    }
    __syncthreads();
    if (t < 32) {
        const float Z = zred[0][t >> 4][t & 15] + zred[1][t >> 4][t & 15]
                      + zred[2][t >> 4][t & 15] + zred[3][t >> 4][t & 15];
        wsf[L2Z_OFFF + (size_t)db * N_ + nc0 * 32 + t] = -__log2f(Z);
    }
}

// ---------------------------------------------------------------------------
// Kernel 3: out = f + beta * V · E,  E[n,m] = exp2(q·k - log2Z) computed ONCE.
// Block tile 256c x 32m (full C -> zero E duplication), 4 waves x 64c.
// Per kstep: wave w E-gens its 16-n slice (2 padded MFMAs, l2z in C-operand,
// 8 exp2) -> ONE barrier (Es double-buffered) -> all waves consume full E
// (4 ds_read_b128 + 16 main MFMAs). Global frag loads issue right after the
// barrier so the next barrier's vmcnt(0) drain finds them complete.
// grid(128 m-tiles, 1, 4 db) = 512 blocks, 2 blocks/CU.
// ---------------------------------------------------------------------------
#define ESTR 72

__global__ __launch_bounds__(256) void attn_gemm(
    const float* __restrict__ fL, const float* __restrict__ fU,
    const float* __restrict__ betap,
    const unsigned short* __restrict__ wsu,
    const float* __restrict__ wsf,
    float* __restrict__ out)
{
    const int db = blockIdx.z;
    const int d  = db >> 1;
    const int b  = db & 1;
    const int t  = threadIdx.x;
    const int w  = t >> 6;
    const int l  = t & 63;
    const int lm = l & 15;
    const int q  = l >> 4;
    const int m0 = blockIdx.x * 32;

    const unsigned short* qF = wsu + QF_OFF + (size_t)db * 256 * 512;
    const unsigned short* kF = wsu + KF_OFF + (size_t)db * 256 * 512;
    const unsigned short* VF = wsu + VF_OFF + (size_t)db * 16 * 128 * 512;
    const float* l2z = wsf + L2Z_OFFF + (size_t)db * N_;
    const float* f = ((d == 0) ? fL : fU) + (size_t)b * C_ * N_;
    float*       o = out + (size_t)db * C_ * N_;

    __shared__ __align__(16) unsigned short Es[2][32 * ESTR];

    // persistent k-frags (this block's 32 m; zero quads baked into kF)
    short8 kf[2];
#pragma unroll
    for (int mb = 0; mb < 2; mb++)
        kf[mb] = *reinterpret_cast<const short8*>(
            kF + (size_t)(blockIdx.x * 2 + mb) * 512 + l * 8);

    // A-frag bases: wave w owns c-tiles w*4..w*4+3
    const unsigned short* Ab[4];
#pragma unroll
    for (int cb = 0; cb < 4; cb++)
        Ab[cb] = VF + (size_t)(w * 4 + cb) * 128 * 512 + l * 8;

    f32x4 acc[4][2];
#pragma unroll
    for (int cb = 0; cb < 4; cb++)
#pragma unroll
        for (int mb = 0; mb < 2; mb++) acc[cb][mb] = f32x4{0.f, 0.f, 0.f, 0.f};

    short8 A0[8], A1[8], q0, q1;
    f32x4  z0, z1;

    auto loadA = [&](short8* A, int i) {
        const int nc = (i & 63) * 2;
#pragma unroll
        for (int cb = 0; cb < 4; cb++)
#pragma unroll
            for (int kc = 0; kc < 2; kc++)
                A[cb * 2 + kc] = *reinterpret_cast<const short8*>(
                    Ab[cb] + (size_t)(nc + kc) * 512);
    };
    auto loadQZ = [&](short8& qf_, f32x4& zf_, int i) {
        const int ii = i & 63;
        qf_ = *reinterpret_cast<const short8*>(qF + (size_t)(ii * 4 + w) * 512 + l * 8);
        zf_ = *reinterpret_cast<const f32x4*>(l2z + ii * 64 + w * 16 + q * 4);
    };
    auto egen = [&](const short8& qf_, const f32x4& zf_, unsigned short* Eb) {
#pragma unroll
        for (int mb = 0; mb < 2; mb++) {
            const f32x4 sv = MFMA16(qf_, kf[mb], zf_);
            uint2 p;
            p.x = pk2(EXP2F(sv[0]), EXP2F(sv[1]));
            p.y = pk2(EXP2F(sv[2]), EXP2F(sv[3]));
            *reinterpret_cast<uint2*>(Eb + (mb * 16 + lm) * ESTR + w * 16 + q * 4) = p;
        }
    };
    auto mainm = [&](const short8* A, const unsigned short* Eb) {
        short8 Bf[2][2];
#pragma unroll
        for (int mb = 0; mb < 2; mb++)
#pragma unroll
            for (int kc = 0; kc < 2; kc++)
                Bf[mb][kc] = *reinterpret_cast<const short8*>(
                    Eb + (mb * 16 + lm) * ESTR + kc * 32 + q * 8);
#pragma unroll
        for (int kc = 0; kc < 2; kc++)
#pragma unroll
            for (int cb = 0; cb < 4; cb++)
#pragma unroll
                for (int mb = 0; mb < 2; mb++)
                    acc[cb][mb] = MFMA16(A[cb * 2 + kc], Bf[mb][kc], acc[cb][mb]);
    };

    loadA(A0, 0);
    loadQZ(q0, z0, 0);

    for (int i = 0; i < 64; i += 2) {
        egen(q0, z0, Es[0]);
        __syncthreads();
        loadA(A1, i + 1); loadQZ(q1, z1, i + 1);
        mainm(A0, Es[0]);

        egen(q1, z1, Es[1]);
        __syncthreads();
        loadA(A0, i + 2); loadQZ(q0, z0, i + 2);
        mainm(A1, Es[1]);
    }

    // epilogue: out = f + beta * acc  (D rows c = q*4+r, col m = lm)
    const float beta = *betap;
#pragma unroll
    for (int cb = 0; cb < 4; cb++) {
#pragma unroll
        for (int mb = 0; mb < 2; mb++) {
            const int c = w * 64 + cb * 16 + q * 4;
            const int m = m0 + mb * 16 + lm;
#pragma unroll
            for (int r = 0; r < 4; r++) {
                const size_t off = (size_t)(c + r) * N_ + m;
                o[off] = f[off] + beta * acc[cb][mb][r];
            }
        }
    }
}

// ---------------------------------------------------------------------------
extern "C" void kernel_launch(void* const* d_in, const int* in_sizes, int n_in,
                              void* d_out, int out_size, void* d_ws, size_t ws_size,
                              hipStream_t stream)
{
    const float* fL   = (const float*)d_in[0];
    const float* fU   = (const float*)d_in[1];
    const float* qL_w = (const float*)d_in[2];
    const float* qL_b = (const float*)d_in[3];
    const float* kU_w = (const float*)d_in[4];
    const float* kU_b = (const float*)d_in[5];
    const float* vU_w = (const float*)d_in[6];
    const float* vU_b = (const float*)d_in[7];
    const float* qU_w = (const float*)d_in[8];
    const float* qU_b = (const float*)d_in[9];
    const float* kL_w = (const float*)d_in[10];
    const float* kL_b = (const float*)d_in[11];
    const float* vL_w = (const float*)d_in[12];
    const float* vL_b = (const float*)d_in[13];
    const float* beta = (const float*)d_in[14];

    unsigned short* wsu  = (unsigned short*)d_ws;
    float*          wsf  = (float*)d_ws;
    float*          outf = (float*)d_out;

    fused_pre<<<dim3(128, 1, 4), 256, 0, stream>>>(
        fL, fU, qL_w, qL_b, kL_w, kL_b, vL_w, vL_b,
        qU_w, qU_b, kU_w, kU_b, vU_w, vU_b, wsu);

    zcalc<<<dim3(128, B_, 2), 256, 0, stream>>>(wsu, wsf);

    attn_gemm<<<dim3(128, 1, 4), 256, 0, stream>>>(
        fL, fU, beta, wsu, wsf, outf);
}